// Round 1
// baseline (3599.986 us; speedup 1.0000x reference)
//
#include <hip/hip_runtime.h>

#define NFK 512   // num features (K of first GEMM)
#define PDK 64    // projection dim
#define NCK 32    // num classes
#define INTN 15
#define TOTN 31

// tanh(4y) = 1 - 2/(exp(8y)+1). __expf saturates to +inf/0 so limits -> +/-1 correctly.
__device__ __forceinline__ float tanh4_fast(float y) {
    float e = __expf(8.0f * y);
    return 1.0f - __fdividef(2.0f, e + 1.0f);
}

// K1: ppT[p][b] = (1/64) * sum_k x[b][k] * Z[k][p]
// 64 rows x 64 cols per block, 256 threads, K staged in 64-chunks.
__global__ __launch_bounds__(256) void gemm_pp_kernel(
    const float* __restrict__ x, const float* __restrict__ Z,
    float* __restrict__ ppT, int Bn)
{
    __shared__ float xs[64][68];  // [k][row], transposed at staging; pad 68 keeps 16B align
    __shared__ float zs[64][68];  // [k][col]
    const int t  = threadIdx.x;
    const int tx = t & 15;        // row(b) quad
    const int ty = t >> 4;        // col(p) quad
    const int brow = blockIdx.x * 64;

    float acc[4][4];
    #pragma unroll
    for (int i = 0; i < 4; ++i)
        #pragma unroll
        for (int j = 0; j < 4; ++j) acc[i][j] = 0.0f;

    for (int k0 = 0; k0 < NFK; k0 += 64) {
        // stage x tile transposed: thread (kq=tx, row=ty + 16u)
        #pragma unroll
        for (int u = 0; u < 4; ++u) {
            int row  = ty + u * 16;
            int grow = brow + row;
            float4 xv = make_float4(0.f, 0.f, 0.f, 0.f);
            if (grow < Bn)
                xv = *(const float4*)&x[(size_t)grow * NFK + k0 + tx * 4];
            xs[tx * 4 + 0][row] = xv.x;
            xs[tx * 4 + 1][row] = xv.y;
            xs[tx * 4 + 2][row] = xv.z;
            xs[tx * 4 + 3][row] = xv.w;
        }
        // stage Z tile direct: zs[k][col]
        #pragma unroll
        for (int u = 0; u < 4; ++u) {
            int kz = ty + u * 16;
            float4 zv = *(const float4*)&Z[(size_t)(k0 + kz) * PDK + tx * 4];
            *(float4*)&zs[kz][tx * 4] = zv;
        }
        __syncthreads();
        #pragma unroll 16
        for (int kk = 0; kk < 64; ++kk) {
            float4 xf = *(const float4*)&xs[kk][tx * 4];   // per-lane, 2-way banked (free)
            float4 zf = *(const float4*)&zs[kk][ty * 4];   // broadcast within 16-lane groups
            acc[0][0] = fmaf(xf.x, zf.x, acc[0][0]); acc[0][1] = fmaf(xf.x, zf.y, acc[0][1]);
            acc[0][2] = fmaf(xf.x, zf.z, acc[0][2]); acc[0][3] = fmaf(xf.x, zf.w, acc[0][3]);
            acc[1][0] = fmaf(xf.y, zf.x, acc[1][0]); acc[1][1] = fmaf(xf.y, zf.y, acc[1][1]);
            acc[1][2] = fmaf(xf.y, zf.z, acc[1][2]); acc[1][3] = fmaf(xf.y, zf.w, acc[1][3]);
            acc[2][0] = fmaf(xf.z, zf.x, acc[2][0]); acc[2][1] = fmaf(xf.z, zf.y, acc[2][1]);
            acc[2][2] = fmaf(xf.z, zf.z, acc[2][2]); acc[2][3] = fmaf(xf.z, zf.w, acc[2][3]);
            acc[3][0] = fmaf(xf.w, zf.x, acc[3][0]); acc[3][1] = fmaf(xf.w, zf.y, acc[3][1]);
            acc[3][2] = fmaf(xf.w, zf.z, acc[3][2]); acc[3][3] = fmaf(xf.w, zf.w, acc[3][3]);
        }
        __syncthreads();
    }

    // epilogue: scale 1/64, store ppT[p][b] coalesced float4 across tx
    const int b4 = brow + tx * 4;
    if (b4 < Bn) {   // Bn % 4 == 0, so whole-float4 guard is exact
        #pragma unroll
        for (int j = 0; j < 4; ++j) {
            int p = ty * 4 + j;
            float4 o = make_float4(acc[0][j], acc[1][j], acc[2][j], acc[3][j]);
            o.x *= 0.015625f; o.y *= 0.015625f; o.z *= 0.015625f; o.w *= 0.015625f;
            *(float4*)&ppT[(size_t)p * Bn + b4] = o;
        }
    }
}

// K2: one thread per batch element. pp row in regs; W/V loads are wave-uniform
// (should scalarize to s_load feeding v_fmac v,s,v). Columns split 16+16 to
// bound VGPR use (~190) and avoid spills.
__global__ __launch_bounds__(64) void bonsai_fused_kernel(
    const float* __restrict__ ppT, const float* __restrict__ T,
    const float* __restrict__ V, const float* __restrict__ W,
    float* __restrict__ out, int Bn)
{
    const int b = blockIdx.x * 64 + threadIdx.x;
    const bool active = (b < Bn);
    const int bb = active ? b : (Bn - 1);

    float pp[PDK];
    #pragma unroll
    for (int p = 0; p < PDK; ++p) pp[p] = ppT[(size_t)p * Bn + bb];  // coalesced

    // tree indicator branch values
    float tb[INTN];
    #pragma unroll
    for (int j = 0; j < INTN; ++j) {
        float d = 0.0f;
        #pragma unroll
        for (int p = 0; p < PDK; ++p) d = fmaf(pp[p], T[j * PDK + p], d);
        tb[j] = tanh4_fast(d);
    }
    float I[TOTN];
    I[0] = 1.0f;
    #pragma unroll
    for (int i = 1; i < TOTN; ++i) {
        int j = (i - 1) >> 1;                       // parent
        float s = (i & 1) ? tb[j] : -tb[j];         // left child +, right child -
        I[i] = 0.5f * I[j] * (1.0f + s);
    }

    float acc[NCK];
    #pragma unroll
    for (int c = 0; c < NCK; ++c) acc[c] = 0.0f;

    #pragma unroll   // MUST fully unroll: acc[] index depends on 'half' (rule: no runtime reg-array idx)
    for (int half = 0; half < 2; ++half) {
        const float* Wh = W + half * 16;
        const float* Vh = V + half * 16;
        #pragma unroll 1
        for (int n = 0; n < TOTN; ++n) {
            float aw[16], av[16];
            #pragma unroll
            for (int c = 0; c < 16; ++c) { aw[c] = 0.0f; av[c] = 0.0f; }
            const float* Wn = Wh + n * (PDK * NCK);
            const float* Vn = Vh + n * (PDK * NCK);
            #pragma unroll
            for (int p = 0; p < PDK; ++p) {
                const float ppv = pp[p];
                #pragma unroll
                for (int c = 0; c < 16; ++c) {
                    aw[c] = fmaf(ppv, Wn[p * NCK + c], aw[c]);
                    av[c] = fmaf(ppv, Vn[p * NCK + c], av[c]);
                }
            }
            const float In = I[n];
            #pragma unroll
            for (int c = 0; c < 16; ++c)
                acc[half * 16 + c] = fmaf(aw[c] * tanh4_fast(av[c]), In, acc[half * 16 + c]);
        }
    }

    if (active) {
        #pragma unroll
        for (int c4 = 0; c4 < 8; ++c4) {
            float4 o = make_float4(acc[c4 * 4 + 0], acc[c4 * 4 + 1],
                                   acc[c4 * 4 + 2], acc[c4 * 4 + 3]);
            *(float4*)&out[(size_t)b * NCK + c4 * 4] = o;
        }
    }
}

extern "C" void kernel_launch(void* const* d_in, const int* in_sizes, int n_in,
                              void* d_out, int out_size, void* d_ws, size_t ws_size,
                              hipStream_t stream)
{
    const float* x = (const float*)d_in[0];
    const float* Z = (const float*)d_in[1];
    const float* T = (const float*)d_in[2];
    const float* V = (const float*)d_in[3];
    const float* W = (const float*)d_in[4];
    float* out = (float*)d_out;
    const int Bn = in_sizes[0] / NFK;

    float* ppT = (float*)d_ws;   // needs 64 * Bn * 4 = 25.6 MB of workspace

    const int nblk = (Bn + 63) / 64;
    gemm_pp_kernel<<<nblk, 256, 0, stream>>>(x, Z, ppT, Bn);
    bonsai_fused_kernel<<<nblk, 64, 0, stream>>>(ppT, T, V, W, out, Bn);
}

// Round 2
// 827.621 us; speedup vs baseline: 4.3498x; 4.3498x over previous
//
#include <hip/hip_runtime.h>

#define NFK 512   // num features
#define PDK 64    // projection dim
#define NCK 32    // num classes
#define INTN 15
#define TOTN 31
#define ROWS 128  // batch rows per block in fused kernel

// tanh(4y) = 1 - 2/(exp(8y)+1). __expf saturates cleanly at +/-inf.
__device__ __forceinline__ float tanh4_fast(float y) {
    float e = __expf(8.0f * y);
    return 1.0f - __fdividef(2.0f, e + 1.0f);
}

// ---------------------------------------------------------------------------
// K1: ppT[p][b] = (1/64) * sum_k x[b][k] * Z[k][p]   (unchanged from R1)
// ---------------------------------------------------------------------------
__global__ __launch_bounds__(256) void gemm_pp_kernel(
    const float* __restrict__ x, const float* __restrict__ Z,
    float* __restrict__ ppT, int Bn)
{
    __shared__ __align__(16) float xs[64][68];
    __shared__ __align__(16) float zs[64][68];
    const int t  = threadIdx.x;
    const int tx = t & 15;
    const int ty = t >> 4;
    const int brow = blockIdx.x * 64;

    float acc[4][4];
    #pragma unroll
    for (int i = 0; i < 4; ++i)
        #pragma unroll
        for (int j = 0; j < 4; ++j) acc[i][j] = 0.0f;

    for (int k0 = 0; k0 < NFK; k0 += 64) {
        #pragma unroll
        for (int u = 0; u < 4; ++u) {
            int row  = ty + u * 16;
            int grow = brow + row;
            float4 xv = make_float4(0.f, 0.f, 0.f, 0.f);
            if (grow < Bn)
                xv = *(const float4*)&x[(size_t)grow * NFK + k0 + tx * 4];
            xs[tx * 4 + 0][row] = xv.x;
            xs[tx * 4 + 1][row] = xv.y;
            xs[tx * 4 + 2][row] = xv.z;
            xs[tx * 4 + 3][row] = xv.w;
        }
        #pragma unroll
        for (int u = 0; u < 4; ++u) {
            int kz = ty + u * 16;
            float4 zv = *(const float4*)&Z[(size_t)(k0 + kz) * PDK + tx * 4];
            *(float4*)&zs[kz][tx * 4] = zv;
        }
        __syncthreads();
        #pragma unroll 16
        for (int kk = 0; kk < 64; ++kk) {
            float4 xf = *(const float4*)&xs[kk][tx * 4];
            float4 zf = *(const float4*)&zs[kk][ty * 4];
            acc[0][0] = fmaf(xf.x, zf.x, acc[0][0]); acc[0][1] = fmaf(xf.x, zf.y, acc[0][1]);
            acc[0][2] = fmaf(xf.x, zf.z, acc[0][2]); acc[0][3] = fmaf(xf.x, zf.w, acc[0][3]);
            acc[1][0] = fmaf(xf.y, zf.x, acc[1][0]); acc[1][1] = fmaf(xf.y, zf.y, acc[1][1]);
            acc[1][2] = fmaf(xf.y, zf.z, acc[1][2]); acc[1][3] = fmaf(xf.y, zf.w, acc[1][3]);
            acc[2][0] = fmaf(xf.z, zf.x, acc[2][0]); acc[2][1] = fmaf(xf.z, zf.y, acc[2][1]);
            acc[2][2] = fmaf(xf.z, zf.z, acc[2][2]); acc[2][3] = fmaf(xf.z, zf.w, acc[2][3]);
            acc[3][0] = fmaf(xf.w, zf.x, acc[3][0]); acc[3][1] = fmaf(xf.w, zf.y, acc[3][1]);
            acc[3][2] = fmaf(xf.w, zf.z, acc[3][2]); acc[3][3] = fmaf(xf.w, zf.w, acc[3][3]);
        }
        __syncthreads();
    }

    const int b4 = brow + tx * 4;
    if (b4 < Bn) {
        #pragma unroll
        for (int j = 0; j < 4; ++j) {
            int p = ty * 4 + j;
            float4 o = make_float4(acc[0][j], acc[1][j], acc[2][j], acc[3][j]);
            o.x *= 0.015625f; o.y *= 0.015625f; o.z *= 0.015625f; o.w *= 0.015625f;
            *(float4*)&ppT[(size_t)p * Bn + b4] = o;
        }
    }
}

// ---------------------------------------------------------------------------
// K2: GEMM-structured fused einsum. Block = 128 batch rows, 256 threads.
// pp tile + per-node W/V tiles in LDS; 2row x 8col register tile per thread.
// Per k-step: 1 ds_read_b64 + 4 ds_read_b128 (broadcast) -> 32 v_fma_f32.
// W/V double-buffered with issue-early / write-late staging (T14).
// LDS: 32K (ppS) + 15.5K (IS) + 16K (WS) + 16K (VS) = 81.4 KB -> 2 blocks/CU.
// ---------------------------------------------------------------------------
__global__ __launch_bounds__(256) void bonsai_fused2(
    const float* __restrict__ ppT, const float* __restrict__ T,
    const float* __restrict__ V, const float* __restrict__ W,
    float* __restrict__ out, int Bn)
{
    __shared__ __align__(16) float ppS[PDK][ROWS];    // [k][row]  32 KB
    __shared__ __align__(16) float IS[TOTN][ROWS];    // 15.5 KB
    __shared__ __align__(16) float WS[2][PDK][NCK];   // 16 KB
    __shared__ __align__(16) float VS[2][PDK][NCK];   // 16 KB

    const int t = threadIdx.x;
    const int brow = blockIdx.x * ROWS;

    // ---- stage pp tile: ppS[p][r] = ppT[p][brow+r], coalesced float4 ----
    #pragma unroll
    for (int u = 0; u < 8; ++u) {
        int idx = u * 256 + t;          // 0..2047 float4 slots
        int p = idx >> 5;               // 64 p-rows
        int r = (idx & 31) * 4;         // 128 rows / 4
        float4 v = make_float4(0.f, 0.f, 0.f, 0.f);
        if (brow + r + 3 < Bn)          // Bn % 4 == 0 so no partial float4
            v = *(const float4*)&ppT[(size_t)p * Bn + brow + r];
        *(float4*)&ppS[p][r] = v;
    }
    __syncthreads();

    // ---- tree indicators (t<128: one row each) || stage node-0 W/V (t>=128) ----
    if (t < ROWS) {
        const int r = t;
        float tb[INTN];
        #pragma unroll
        for (int j = 0; j < INTN; ++j) {
            float d = 0.f;
            #pragma unroll
            for (int p = 0; p < PDK; ++p)
                d = fmaf(ppS[p][r], T[j * PDK + p], d);   // T wave-uniform -> s_load
            tb[j] = tanh4_fast(d);
        }
        float I[TOTN];
        I[0] = 1.f;
        #pragma unroll
        for (int i = 1; i < TOTN; ++i) {
            int j = (i - 1) >> 1;
            float s = (i & 1) ? tb[j] : -tb[j];   // 0-based: odd = left(+), even = right(-)
            I[i] = 0.5f * I[j] * (1.f + s);
        }
        #pragma unroll
        for (int i = 0; i < TOTN; ++i) IS[i][r] = I[i];
    } else {
        const int tt = t - 128;          // 0..127, stage 512 float4 per buffer
        #pragma unroll
        for (int u = 0; u < 4; ++u) {
            int idx = u * 128 + tt;
            ((float4*)&WS[0][0][0])[idx] = ((const float4*)W)[idx];
            ((float4*)&VS[0][0][0])[idx] = ((const float4*)V)[idx];
        }
    }
    __syncthreads();

    const int colg = t & 3;              // 4 col-groups x 8 cols
    const int rowg = t >> 2;             // 64 row-groups x 2 rows
    const int c0 = colg * 8;
    const int r0 = rowg * 2;

    float acc[2][8];
    #pragma unroll
    for (int i = 0; i < 2; ++i)
        #pragma unroll
        for (int c = 0; c < 8; ++c) acc[i][c] = 0.f;

    float4 wpre[2], vpre[2];

    for (int n = 0; n < TOTN; ++n) {
        const int cur = n & 1;

        // T14: issue next node's global loads now; LDS-write after compute.
        if (n + 1 < TOTN) {
            const float4* Wn = (const float4*)(W + (size_t)(n + 1) * PDK * NCK);
            const float4* Vn = (const float4*)(V + (size_t)(n + 1) * PDK * NCK);
            #pragma unroll
            for (int u = 0; u < 2; ++u) {
                wpre[u] = Wn[u * 256 + t];
                vpre[u] = Vn[u * 256 + t];
            }
        }

        float aw[2][8], av[2][8];
        #pragma unroll
        for (int i = 0; i < 2; ++i)
            #pragma unroll
            for (int c = 0; c < 8; ++c) { aw[i][c] = 0.f; av[i][c] = 0.f; }

        #pragma unroll 8
        for (int k = 0; k < PDK; ++k) {
            const float2 pv = *(const float2*)&ppS[k][r0];
            const float4 wa = *(const float4*)&WS[cur][k][c0];
            const float4 wb = *(const float4*)&WS[cur][k][c0 + 4];
            const float4 va = *(const float4*)&VS[cur][k][c0];
            const float4 vb = *(const float4*)&VS[cur][k][c0 + 4];
            const float w8[8] = {wa.x, wa.y, wa.z, wa.w, wb.x, wb.y, wb.z, wb.w};
            const float v8[8] = {va.x, va.y, va.z, va.w, vb.x, vb.y, vb.z, vb.w};
            #pragma unroll
            for (int c = 0; c < 8; ++c) {
                aw[0][c] = fmaf(pv.x, w8[c], aw[0][c]);
                aw[1][c] = fmaf(pv.y, w8[c], aw[1][c]);
                av[0][c] = fmaf(pv.x, v8[c], av[0][c]);
                av[1][c] = fmaf(pv.y, v8[c], av[1][c]);
            }
        }

        const float I0 = IS[n][r0], I1 = IS[n][r0 + 1];
        #pragma unroll
        for (int c = 0; c < 8; ++c) {
            acc[0][c] = fmaf(aw[0][c] * tanh4_fast(av[0][c]), I0, acc[0][c]);
            acc[1][c] = fmaf(aw[1][c] * tanh4_fast(av[1][c]), I1, acc[1][c]);
        }

        // write prefetched node n+1 into the other buffer. Safe without a
        // pre-sync: other waves are reading WS/VS[cur] only; last readers of
        // [cur^1] were iteration n-1, separated by its __syncthreads.
        if (n + 1 < TOTN) {
            #pragma unroll
            for (int u = 0; u < 2; ++u) {
                ((float4*)&WS[cur ^ 1][0][0])[u * 256 + t] = wpre[u];
                ((float4*)&VS[cur ^ 1][0][0])[u * 256 + t] = vpre[u];
            }
        }
        __syncthreads();   // one barrier per node: staged writes visible for n+1
    }

    #pragma unroll
    for (int i = 0; i < 2; ++i) {
        int r = brow + r0 + i;
        if (r < Bn) {
            *(float4*)&out[(size_t)r * NCK + c0] =
                make_float4(acc[i][0], acc[i][1], acc[i][2], acc[i][3]);
            *(float4*)&out[(size_t)r * NCK + c0 + 4] =
                make_float4(acc[i][4], acc[i][5], acc[i][6], acc[i][7]);
        }
    }
}

extern "C" void kernel_launch(void* const* d_in, const int* in_sizes, int n_in,
                              void* d_out, int out_size, void* d_ws, size_t ws_size,
                              hipStream_t stream)
{
    const float* x = (const float*)d_in[0];
    const float* Z = (const float*)d_in[1];
    const float* T = (const float*)d_in[2];
    const float* V = (const float*)d_in[3];
    const float* W = (const float*)d_in[4];
    float* out = (float*)d_out;
    const int Bn = in_sizes[0] / NFK;

    float* ppT = (float*)d_ws;   // 64 * Bn * 4 = 25.6 MB scratch

    gemm_pp_kernel<<<(Bn + 63) / 64, 256, 0, stream>>>(x, Z, ppT, Bn);
    bonsai_fused2<<<(Bn + ROWS - 1) / ROWS, 256, 0, stream>>>(ppT, T, V, W, out, Bn);
}

// Round 3
// 790.583 us; speedup vs baseline: 4.5536x; 1.0468x over previous
//
#include <hip/hip_runtime.h>

#define NFK 512   // num features
#define PDK 64    // projection dim
#define NCK 32    // num classes
#define INTN 15
#define TOTN 31
#define ROWS 128  // batch rows per block

// tanh(4y) = 1 - 2/(exp(8y)+1). __expf saturates cleanly at +/-inf.
__device__ __forceinline__ float tanh4_fast(float y) {
    float e = __expf(8.0f * y);
    return 1.0f - __fdividef(2.0f, e + 1.0f);
}

struct PhaseA {                    // 25.6 KB
    float xT[32][132];             // k-major x tile, padded (staging-write conflicts)
    float Zs[32][68];              // Z tile, padded
};
struct PhaseB {                    // 31.5 KB
    float WS[PDK][NCK];            // current node W   (8 KB)
    float VS[PDK][NCK];            // current node V   (8 KB)
    float IS[TOTN][ROWS];          // tree indicators  (15.5 KB)
};

// LDS total: ppS 33 KB + union 31.5 KB = 64.5 KB -> 2 blocks/CU (8 waves/CU).
__global__ __launch_bounds__(256, 2) void bonsai_one(
    const float* __restrict__ x, const float* __restrict__ Z,
    const float* __restrict__ T, const float* __restrict__ V,
    const float* __restrict__ W, float* __restrict__ out, int Bn)
{
    __shared__ __align__(16) float ppS[PDK][132];   // [k][row], pad 132
    __shared__ __align__(16) union { PhaseA a; PhaseB b; } U;

    const int t = threadIdx.x;
    const int brow = blockIdx.x * ROWS;

    // ===================== Phase A: pp = (x @ Z) / 64 =====================
    // thread tile: 4 p-cols x 8 rows. 16 p-groups x 16 r-groups = 256 thr.
    {
        const int pa0 = (t & 15) * 4;
        const int ra0 = (t >> 4) * 8;
        float pacc[4][8];
        #pragma unroll
        for (int i = 0; i < 4; ++i)
            #pragma unroll
            for (int j = 0; j < 8; ++j) pacc[i][j] = 0.f;

        for (int k0 = 0; k0 < NFK; k0 += 32) {
            // stage xT[kk][r] (transpose at write; padded stride kills conflicts)
            #pragma unroll
            for (int u = 0; u < 4; ++u) {
                int idx = u * 256 + t;         // 0..1023 float4 slots
                int r = idx >> 3, kq = idx & 7;
                float4 xv = make_float4(0.f, 0.f, 0.f, 0.f);
                if (brow + r < Bn)
                    xv = *(const float4*)&x[(size_t)(brow + r) * NFK + k0 + kq * 4];
                U.a.xT[kq * 4 + 0][r] = xv.x;
                U.a.xT[kq * 4 + 1][r] = xv.y;
                U.a.xT[kq * 4 + 2][r] = xv.z;
                U.a.xT[kq * 4 + 3][r] = xv.w;
            }
            // stage Zs[kk][p]
            #pragma unroll
            for (int u = 0; u < 2; ++u) {
                int idx = u * 256 + t;         // 0..511 float4 slots
                int kk = idx >> 4, p4 = idx & 15;
                *(float4*)&U.a.Zs[kk][p4 * 4] =
                    *(const float4*)&Z[(size_t)(k0 + kk) * PDK + p4 * 4];
            }
            __syncthreads();
            #pragma unroll 8
            for (int kk = 0; kk < 32; ++kk) {
                const float4 zq = *(const float4*)&U.a.Zs[kk][pa0];
                const float4 xa = *(const float4*)&U.a.xT[kk][ra0];
                const float4 xb = *(const float4*)&U.a.xT[kk][ra0 + 4];
                const float x8[8] = {xa.x, xa.y, xa.z, xa.w, xb.x, xb.y, xb.z, xb.w};
                const float z4[4] = {zq.x, zq.y, zq.z, zq.w};
                #pragma unroll
                for (int i = 0; i < 4; ++i)
                    #pragma unroll
                    for (int j = 0; j < 8; ++j)
                        pacc[i][j] = fmaf(z4[i], x8[j], pacc[i][j]);
            }
            __syncthreads();
        }
        // write ppS[p][r] scaled by 1/64
        #pragma unroll
        for (int i = 0; i < 4; ++i) {
            #pragma unroll
            for (int q = 0; q < 2; ++q) {
                float4 o = make_float4(pacc[i][q*4+0], pacc[i][q*4+1],
                                       pacc[i][q*4+2], pacc[i][q*4+3]);
                o.x *= 0.015625f; o.y *= 0.015625f; o.z *= 0.015625f; o.w *= 0.015625f;
                *(float4*)&ppS[pa0 + i][ra0 + q * 4] = o;
            }
        }
    }
    __syncthreads();   // ppS complete; xT/Zs dead -> union flips to PhaseB

    // ===== tree indicators (t<128: one row each) || node-0 W/V staging =====
    if (t < ROWS) {
        const int r = t;
        float ppr[PDK];
        #pragma unroll
        for (int p = 0; p < PDK; ++p) ppr[p] = ppS[p][r];   // conflict-free columns
        float I[TOTN];
        I[0] = 1.f;
        #pragma unroll
        for (int j = 0; j < INTN; ++j) {        // parent j before children 2j+1/2j+2
            float d = 0.f;
            #pragma unroll
            for (int p = 0; p < PDK; ++p)
                d = fmaf(ppr[p], T[j * PDK + p], d);        // T uniform -> scalarized
            float tb = tanh4_fast(d);
            I[2 * j + 1] = 0.5f * I[j] * (1.f + tb);
            I[2 * j + 2] = 0.5f * I[j] * (1.f - tb);
        }
        #pragma unroll
        for (int i = 0; i < TOTN; ++i) U.b.IS[i][r] = I[i];
    } else {
        const int tt = t - 128;
        const float4* W4 = (const float4*)W;    // node 0 at offset 0
        const float4* V4 = (const float4*)V;
        #pragma unroll
        for (int u = 0; u < 4; ++u) {
            ((float4*)U.b.WS)[u * 128 + tt] = W4[u * 128 + tt];
            ((float4*)U.b.VS)[u * 128 + tt] = V4[u * 128 + tt];
        }
    }
    __syncthreads();

    // ===================== Phase B: per-node einsums =====================
    // thread tile: 4 rows x 4 cols. 32 row-groups x 8 col-groups = 256 thr.
    const int c0 = (t & 7) * 4;
    const int r0 = (t >> 3) * 4;

    float acc[4][4];
    #pragma unroll
    for (int i = 0; i < 4; ++i)
        #pragma unroll
        for (int c = 0; c < 4; ++c) acc[i][c] = 0.f;

    for (int n = 0; n < TOTN; ++n) {
        // T14: issue next node's loads now; LDS-write after the barrier.
        float4 wpre0, wpre1, vpre0, vpre1;
        if (n + 1 < TOTN) {
            const float4* Wn = (const float4*)(W + (size_t)(n + 1) * PDK * NCK);
            const float4* Vn = (const float4*)(V + (size_t)(n + 1) * PDK * NCK);
            wpre0 = Wn[t]; wpre1 = Wn[256 + t];
            vpre0 = Vn[t]; vpre1 = Vn[256 + t];
        }

        float aw[4][4], av[4][4];
        #pragma unroll
        for (int i = 0; i < 4; ++i)
            #pragma unroll
            for (int c = 0; c < 4; ++c) { aw[i][c] = 0.f; av[i][c] = 0.f; }

        #pragma unroll 8
        for (int kk = 0; kk < PDK; ++kk) {
            const float4 pq = *(const float4*)&ppS[kk][r0];       // 8-addr broadcast
            const float4 wq = *(const float4*)&U.b.WS[kk][c0];    // 8-addr broadcast
            const float4 vq = *(const float4*)&U.b.VS[kk][c0];
            const float p4[4] = {pq.x, pq.y, pq.z, pq.w};
            const float w4[4] = {wq.x, wq.y, wq.z, wq.w};
            const float v4[4] = {vq.x, vq.y, vq.z, vq.w};
            #pragma unroll
            for (int i = 0; i < 4; ++i)
                #pragma unroll
                for (int c = 0; c < 4; ++c) {
                    aw[i][c] = fmaf(p4[i], w4[c], aw[i][c]);
                    av[i][c] = fmaf(p4[i], v4[c], av[i][c]);
                }
        }

        const float4 Iq = *(const float4*)&U.b.IS[n][r0];
        const float I4[4] = {Iq.x, Iq.y, Iq.z, Iq.w};
        #pragma unroll
        for (int i = 0; i < 4; ++i)
            #pragma unroll
            for (int c = 0; c < 4; ++c)
                acc[i][c] = fmaf(aw[i][c] * tanh4_fast(av[i][c]), I4[i], acc[i][c]);

        __syncthreads();                       // all reads of WS/VS[n] done
        if (n + 1 < TOTN) {
            ((float4*)U.b.WS)[t]       = wpre0;
            ((float4*)U.b.WS)[256 + t] = wpre1;
            ((float4*)U.b.VS)[t]       = vpre0;
            ((float4*)U.b.VS)[256 + t] = vpre1;
            __syncthreads();                   // staged node n+1 visible
        }
    }

    // ===================== epilogue =====================
    #pragma unroll
    for (int i = 0; i < 4; ++i) {
        int r = brow + r0 + i;
        if (r < Bn)
            *(float4*)&out[(size_t)r * NCK + c0] =
                make_float4(acc[i][0], acc[i][1], acc[i][2], acc[i][3]);
    }
}

extern "C" void kernel_launch(void* const* d_in, const int* in_sizes, int n_in,
                              void* d_out, int out_size, void* d_ws, size_t ws_size,
                              hipStream_t stream)
{
    const float* x = (const float*)d_in[0];
    const float* Z = (const float*)d_in[1];
    const float* T = (const float*)d_in[2];
    const float* V = (const float*)d_in[3];
    const float* W = (const float*)d_in[4];
    float* out = (float*)d_out;
    const int Bn = in_sizes[0] / NFK;

    bonsai_one<<<(Bn + ROWS - 1) / ROWS, 256, 0, stream>>>(x, Z, T, V, W, out, Bn);
}

// Round 4
// 485.382 us; speedup vs baseline: 7.4168x; 1.6288x over previous
//
#include <hip/hip_runtime.h>

#define NFK 512
#define PDK 64
#define NCK 32
#define INTN 15
#define TOTN 31
#define BM1 256   // K1 rows/block
#define BM2 128   // K2 rows/block

typedef __attribute__((ext_vector_type(8))) short bf16x8;   // 8 bf16 = 4 VGPR
typedef __attribute__((ext_vector_type(4))) float f32x4;

__device__ __forceinline__ float tanh4_fast(float y) {
    float e = __expf(8.0f * y);
    return 1.0f - __fdividef(2.0f, e + 1.0f);
}
__device__ __forceinline__ unsigned int f2bf_pair(float lo, float hi) {
    unsigned int a = __float_as_uint(lo), b = __float_as_uint(hi);
    a = (a + 0x7FFF + ((a >> 16) & 1)) >> 16;          // RNE
    b = (b + 0x7FFF + ((b >> 16) & 1)) >> 16;
    return a | (b << 16);
}

// ---------------------------------------------------------------------------
// K0: pack W,V [31][64][32] fp32 -> B-fragment units: dst[n][u][c] = 8 bf16
// {src[n][u*8+j][c], j=0..7}. 62 blocks x 256 thr (bid&1: 0=W,1=V).
// ---------------------------------------------------------------------------
__global__ __launch_bounds__(256) void pack_wv_kernel(
    const float* __restrict__ W, const float* __restrict__ V,
    uint4* __restrict__ Wt, uint4* __restrict__ Vt)
{
    const int n = blockIdx.x >> 1;
    const float* src = (blockIdx.x & 1) ? V : W;
    uint4* dst = (blockIdx.x & 1) ? Vt : Wt;
    const int t = threadIdx.x;
    const int u = t >> 5, c = t & 31;
    float f[8];
    #pragma unroll
    for (int j = 0; j < 8; ++j)
        f[j] = src[(size_t)(n * PDK + u * 8 + j) * NCK + c];
    uint4 pk;
    pk.x = f2bf_pair(f[0], f[1]); pk.y = f2bf_pair(f[2], f[3]);
    pk.z = f2bf_pair(f[4], f[5]); pk.w = f2bf_pair(f[6], f[7]);
    dst[n * 256 + u * 32 + c] = pk;
}

// ---------------------------------------------------------------------------
// K1: pp[b][p] = (x @ Z)/64, fp32 VALU. BM=256, 8x8 thread tile, 256 thr.
// ---------------------------------------------------------------------------
__global__ __launch_bounds__(256) void gemm_pp_kernel(
    const float* __restrict__ x, const float* __restrict__ Z,
    float* __restrict__ pp, int Bn)
{
    __shared__ __align__(16) float xT[32][260];   // [k][r], 260%32=4 -> spread
    __shared__ __align__(16) float zS[32][68];
    const int t = threadIdx.x;
    const int c0 = (t & 7) * 8;
    const int r0 = (t >> 3) * 8;
    const int brow = blockIdx.x * BM1;

    float acc[8][8];
    #pragma unroll
    for (int i = 0; i < 8; ++i)
        #pragma unroll
        for (int j = 0; j < 8; ++j) acc[i][j] = 0.f;

    for (int k0 = 0; k0 < NFK; k0 += 32) {
        #pragma unroll
        for (int q = 0; q < 8; ++q) {             // 2048 float4: x tile
            int id = q * 256 + t;
            int r = id >> 3, kq = id & 7;
            float4 xv = make_float4(0.f, 0.f, 0.f, 0.f);
            if (brow + r < Bn)
                xv = *(const float4*)&x[(size_t)(brow + r) * NFK + k0 + kq * 4];
            xT[kq * 4 + 0][r] = xv.x; xT[kq * 4 + 1][r] = xv.y;
            xT[kq * 4 + 2][r] = xv.z; xT[kq * 4 + 3][r] = xv.w;
        }
        #pragma unroll
        for (int q = 0; q < 2; ++q) {             // 512 float4: Z tile
            int id = q * 256 + t;
            int kk = id >> 4, c4 = id & 15;
            *(float4*)&zS[kk][c4 * 4] =
                *(const float4*)&Z[(size_t)(k0 + kk) * PDK + c4 * 4];
        }
        __syncthreads();
        #pragma unroll 8
        for (int kk = 0; kk < 32; ++kk) {
            const float4 xa = *(const float4*)&xT[kk][r0];
            const float4 xb = *(const float4*)&xT[kk][r0 + 4];
            const float4 za = *(const float4*)&zS[kk][c0];
            const float4 zb = *(const float4*)&zS[kk][c0 + 4];
            const float xr[8] = {xa.x, xa.y, xa.z, xa.w, xb.x, xb.y, xb.z, xb.w};
            const float zc[8] = {za.x, za.y, za.z, za.w, zb.x, zb.y, zb.z, zb.w};
            #pragma unroll
            for (int i = 0; i < 8; ++i)
                #pragma unroll
                for (int j = 0; j < 8; ++j)
                    acc[i][j] = fmaf(xr[i], zc[j], acc[i][j]);
        }
        __syncthreads();
    }
    #pragma unroll
    for (int i = 0; i < 8; ++i) {
        int r = brow + r0 + i;
        if (r < Bn) {
            #pragma unroll
            for (int q = 0; q < 2; ++q) {
                float4 o = make_float4(acc[i][q*4+0], acc[i][q*4+1],
                                       acc[i][q*4+2], acc[i][q*4+3]);
                o.x *= 0.015625f; o.y *= 0.015625f; o.z *= 0.015625f; o.w *= 0.015625f;
                *(float4*)&pp[(size_t)r * PDK + c0 + q * 4] = o;
            }
        }
    }
}

// ---------------------------------------------------------------------------
// K2: MFMA einsum. BM=128 rows, 4 waves (each 32 rows x 32 cols, W and V).
// A-frags (pp, bf16) register-resident across all 31 nodes; per-node B-frags
// from LDS (8 x ds_read_b128/wave); indicators fp32; C/D layout per m89:
// col = lane&15, row = (lane>>4)*4 + reg.
// ---------------------------------------------------------------------------
__global__ __launch_bounds__(256) void bonsai_mfma_kernel(
    const float* __restrict__ pp, const float* __restrict__ T,
    const uint4* __restrict__ Wt, const uint4* __restrict__ Vt,
    float* __restrict__ out, int Bn)
{
    __shared__ __align__(16) float ppF[BM2][68];   // fp32 pp tile (34.8 KB)
    __shared__ __align__(16) uint4 ppA[8 * BM2];   // A-frag units [u][r] (16 KB)
    __shared__ __align__(16) float IS[TOTN][BM2];  // indicators (15.5 KB)
    __shared__ __align__(16) uint4 WVs[2][256];    // node B-frags [arr][u*32+c] (8 KB)

    const int t = threadIdx.x;
    const int brow = blockIdx.x * BM2;

    // 1) stage ppF coalesced (zero-pad tail rows)
    #pragma unroll
    for (int q = 0; q < 8; ++q) {
        int id = q * 256 + t;
        int r = id >> 4, c4 = id & 15;
        float4 v = make_float4(0.f, 0.f, 0.f, 0.f);
        if (brow + r < Bn)
            v = *(const float4*)&pp[(size_t)(brow + r) * PDK + c4 * 4];
        *(float4*)&ppF[r][c4 * 4] = v;
    }
    __syncthreads();

    // 2) build bf16 A-frag units ppA[u*128+r] = {pp[r][u*8..u*8+7]}
    #pragma unroll
    for (int q = 0; q < 4; ++q) {
        int id = q * 256 + t;
        int r = id >> 3, u = id & 7;
        const float* s = &ppF[r][u * 8];
        uint4 pk;
        pk.x = f2bf_pair(s[0], s[1]); pk.y = f2bf_pair(s[2], s[3]);
        pk.z = f2bf_pair(s[4], s[5]); pk.w = f2bf_pair(s[6], s[7]);
        ppA[u * BM2 + r] = pk;
    }

    // 3) indicators (t<128, fp32) || stage node-0 B-frags (t>=128)
    if (t < BM2) {
        const int r = t;
        float ppr[PDK];
        #pragma unroll
        for (int p = 0; p < PDK; ++p) ppr[p] = ppF[r][p];
        float I[TOTN];
        I[0] = 1.f;
        #pragma unroll
        for (int j = 0; j < INTN; ++j) {
            float d = 0.f;
            #pragma unroll
            for (int p = 0; p < PDK; ++p)
                d = fmaf(ppr[p], T[j * PDK + p], d);
            float tb = tanh4_fast(d);
            I[2 * j + 1] = 0.5f * I[j] * (1.f + tb);
            I[2 * j + 2] = 0.5f * I[j] * (1.f - tb);
        }
        #pragma unroll
        for (int i = 0; i < TOTN; ++i) IS[i][r] = I[i];
    } else {
        const int tt = t - BM2;   // 128 threads stage 2x256 units
        WVs[0][tt]       = Wt[tt];
        WVs[0][tt + 128] = Wt[tt + 128];
        WVs[1][tt]       = Vt[tt];
        WVs[1][tt + 128] = Vt[tt + 128];
    }
    __syncthreads();

    // A-frags resident: af[rt][ks], rt = row-tile (16), ks = k-step (32)
    const int lane = t & 63;
    const int wr0 = (t >> 6) * 32;                  // wave's first row
    const int lrow = lane & 15, lgrp = lane >> 4;   // frag row / k-group
    bf16x8 af[2][2];
    #pragma unroll
    for (int rt = 0; rt < 2; ++rt)
        #pragma unroll
        for (int ks = 0; ks < 2; ++ks)
            af[rt][ks] = __builtin_bit_cast(bf16x8,
                ppA[(ks * 4 + lgrp) * BM2 + wr0 + rt * 16 + lrow]);

    f32x4 sc[2][2];
    #pragma unroll
    for (int rt = 0; rt < 2; ++rt)
        #pragma unroll
        for (int ct = 0; ct < 2; ++ct)
            sc[rt][ct] = (f32x4){0.f, 0.f, 0.f, 0.f};

    for (int n = 0; n < TOTN; ++n) {
        uint4 pw, pv;                               // T14 prefetch next node
        if (n + 1 < TOTN) {
            pw = Wt[(n + 1) * 256 + t];
            pv = Vt[(n + 1) * 256 + t];
        }

        // B-frags + MFMA: bidx = (ks*4 + lgrp)*32 + ct*16 + lcol
        f32x4 aw[2][2], av[2][2];
        #pragma unroll
        for (int ct = 0; ct < 2; ++ct) {
            bf16x8 bw0 = __builtin_bit_cast(bf16x8, WVs[0][(0 * 4 + lgrp) * 32 + ct * 16 + lrow]);
            bf16x8 bw1 = __builtin_bit_cast(bf16x8, WVs[0][(1 * 4 + lgrp) * 32 + ct * 16 + lrow]);
            bf16x8 bv0 = __builtin_bit_cast(bf16x8, WVs[1][(0 * 4 + lgrp) * 32 + ct * 16 + lrow]);
            bf16x8 bv1 = __builtin_bit_cast(bf16x8, WVs[1][(1 * 4 + lgrp) * 32 + ct * 16 + lrow]);
            #pragma unroll
            for (int rt = 0; rt < 2; ++rt) {
                f32x4 a = (f32x4){0.f, 0.f, 0.f, 0.f};
                a = __builtin_amdgcn_mfma_f32_16x16x32_bf16(af[rt][0], bw0, a, 0, 0, 0);
                a = __builtin_amdgcn_mfma_f32_16x16x32_bf16(af[rt][1], bw1, a, 0, 0, 0);
                aw[rt][ct] = a;
                f32x4 b = (f32x4){0.f, 0.f, 0.f, 0.f};
                b = __builtin_amdgcn_mfma_f32_16x16x32_bf16(af[rt][0], bv0, b, 0, 0, 0);
                b = __builtin_amdgcn_mfma_f32_16x16x32_bf16(af[rt][1], bv1, b, 0, 0, 0);
                av[rt][ct] = b;
            }
        }

        // combine: sc += aw * tanh4(av) * I[n][row]
        #pragma unroll
        for (int rt = 0; rt < 2; ++rt) {
            const f32x4 Iv = *(const f32x4*)&IS[n][wr0 + rt * 16 + lgrp * 4];
            #pragma unroll
            for (int ct = 0; ct < 2; ++ct)
                #pragma unroll
                for (int j = 0; j < 4; ++j)
                    sc[rt][ct][j] = fmaf(aw[rt][ct][j] * tanh4_fast(av[rt][ct][j]),
                                         Iv[j], sc[rt][ct][j]);
        }

        __syncthreads();                            // done reading WVs[n]
        if (n + 1 < TOTN) {
            WVs[0][t] = pw;
            WVs[1][t] = pv;
            __syncthreads();                        // node n+1 visible
        }
    }

    // epilogue: C/D layout -> out[row][col]
    #pragma unroll
    for (int rt = 0; rt < 2; ++rt)
        #pragma unroll
        for (int j = 0; j < 4; ++j) {
            int row = brow + wr0 + rt * 16 + lgrp * 4 + j;
            if (row < Bn) {
                #pragma unroll
                for (int ct = 0; ct < 2; ++ct)
                    out[(size_t)row * NCK + ct * 16 + lrow] = sc[rt][ct][j];
            }
        }
}

extern "C" void kernel_launch(void* const* d_in, const int* in_sizes, int n_in,
                              void* d_out, int out_size, void* d_ws, size_t ws_size,
                              hipStream_t stream)
{
    const float* x = (const float*)d_in[0];
    const float* Z = (const float*)d_in[1];
    const float* T = (const float*)d_in[2];
    const float* V = (const float*)d_in[3];
    const float* W = (const float*)d_in[4];
    float* out = (float*)d_out;
    const int Bn = in_sizes[0] / NFK;

    float* pp = (float*)d_ws;                           // Bn*64*4 = 25.6 MB
    size_t off = (((size_t)Bn * PDK * 4) + 255) & ~(size_t)255;
    uint4* Wt = (uint4*)((char*)d_ws + off);            // 124 KB
    uint4* Vt = (uint4*)((char*)d_ws + off + TOTN * 256 * sizeof(uint4));

    pack_wv_kernel<<<TOTN * 2, 256, 0, stream>>>(W, V, Wt, Vt);
    gemm_pp_kernel<<<(Bn + BM1 - 1) / BM1, 256, 0, stream>>>(x, Z, pp, Bn);
    bonsai_mfma_kernel<<<(Bn + BM2 - 1) / BM2, 256, 0, stream>>>(pp, T, Wt, Vt, out, Bn);
}